// Round 11
// baseline (60.004 us; speedup 1.0000x reference)
//
#include <hip/hip_runtime.h>
#include <math.h>

#define NB 4096
#define NA 8
#define BN (NB*NA)   // 32768

// ws layout (u32 words)
#define OFF_SE   0            // se pack:  8 tiles * 512
#define OFF_SAP  4096         // sap pack: 8 tiles * 512
#define OFF_AV   8192         // av pack:  8 tiles * 1024
#define OFF_F1   16384        // f1 pack:  4 tiles * 1024
#define OFF_M    20480        // M pack:   8 tiles * 1024
#define OFF_U    28672        // u: 128 floats
#define OFF_W2P  28800        // conv2 weight A-frag pack: 2 ftiles * 1280 (K=160 pad)
// ws end: 31360 words

typedef short short8 __attribute__((ext_vector_type(8)));
typedef float f32x4 __attribute__((ext_vector_type(4)));

#define MFMA(a,b,c) __builtin_amdgcn_mfma_f32_16x16x32_bf16(a,b,c,0,0,0)

__device__ __forceinline__ float fast_tanh(float x){
    float e = __expf(2.0f*x);
    return 1.0f - 2.0f*__builtin_amdgcn_rcpf(e+1.0f);
}
__device__ __forceinline__ unsigned bfr(float x){
    unsigned u = __float_as_uint(x);
    return (u + 0x7fffu + ((u>>16)&1u)) >> 16;
}
__device__ __forceinline__ unsigned pk2(float lo, float hi){
    return bfr(lo) | (bfr(hi)<<16);
}
__device__ __forceinline__ float bf2f(unsigned short s){
    return __uint_as_float(((unsigned)s)<<16);
}
__device__ __forceinline__ short8 fragld(const unsigned* p){
    union { uint4 u; short8 s; } cv;
    cv.u = *(const uint4*)p;
    return cv.s;
}

// ---------------- kW: pack all weights as A-fragments (pack16 of W^T), compute M, u, w2 pack
__global__ __launch_bounds__(256) void kW(const float* __restrict__ se_w,
        const float* __restrict__ sap_w, const float* __restrict__ av_w,
        const float* __restrict__ f1_w, const float* __restrict__ qw,
        const float* __restrict__ kw, const float* __restrict__ qb,
        const float* __restrict__ w2,
        unsigned* __restrict__ ws){
    int idx = blockIdx.x*256 + threadIdx.x;
    if (idx < 4096){                       // sePk (F=64 pad, rows f2=128)
        int w = idx, tile = w>>9, rem = w&511;
        int ft = rem>>6, r2 = (rem>>2)&15, wi = rem&3;
        int f2 = tile*16 + r2, f1 = ft*8 + wi*2;
        float lo = (f1   < 42)? se_w[f1*128+f2]     : 0.f;
        float hi = (f1+1 < 42)? se_w[(f1+1)*128+f2] : 0.f;
        ws[OFF_SE + w] = pk2(lo,hi);
    } else if (idx < 8192){                // sapPk (F=64 pad, limit 47)
        int w = idx-4096, tile = w>>9, rem = w&511;
        int ft = rem>>6, r2 = (rem>>2)&15, wi = rem&3;
        int f2 = tile*16 + r2, f1 = ft*8 + wi*2;
        float lo = (f1   < 47)? sap_w[f1*128+f2]     : 0.f;
        float hi = (f1+1 < 47)? sap_w[(f1+1)*128+f2] : 0.f;
        ws[OFF_SAP + w] = pk2(lo,hi);
    } else if (idx < 16384){               // avPk (F=128)
        int w = idx-8192, tile = w>>10, rem = w&1023;
        int ft = rem>>6, r2 = (rem>>2)&15, wi = rem&3;
        int f2 = tile*16 + r2, f1 = ft*8 + wi*2;
        ws[OFF_AV + w] = pk2(av_w[f1*128+f2], av_w[(f1+1)*128+f2]);
    } else if (idx < 20480){               // f1Pk (F=128, rows f2=64)
        int w = idx-16384, tile = w>>10, rem = w&1023;
        int ft = rem>>6, r2 = (rem>>2)&15, wi = rem&3;
        int f2 = tile*16 + r2, f1 = ft*8 + wi*2;
        ws[OFF_F1 + w] = pk2(f1_w[f1*64+f2], f1_w[(f1+1)*64+f2]);
    } else if (idx < 28672){               // MPk: M[e][f2] = qw[e]·kw[f2]
        int w = idx-20480, tile = w>>10, rem = w&1023;
        int ft = rem>>6, r2 = (rem>>2)&15, wi = rem&3;
        int f2 = tile*16 + r2, e0 = ft*8 + wi*2;
        float lo=0.f, hi=0.f;
        for (int d=0; d<128; ++d){
            float kv = kw[f2*128+d];
            lo += qw[e0*128+d]*kv;
            hi += qw[(e0+1)*128+d]*kv;
        }
        ws[OFF_M + w] = pk2(lo,hi);
    } else if (idx < 28800){               // u[f] = qb·kw[f]
        int f = idx-28672;
        float a = 0.f;
        for (int d=0; d<128; ++d) a += qb[d]*kw[f*128+d];
        ((float*)ws)[OFF_U + f] = a;
    } else if (idx < 31360){               // conv2 weight A-frags: F=32, K=160 (pad from 144)
        int w = idx-28800;
        int ftile = w/1280, rem = w - ftile*1280;
        int ft = rem>>6, r2 = (rem>>2)&15, wi = rem&3;
        int f = ftile*16 + r2, k0 = ft*8 + wi*2;
        float lo = (k0   < 144)? w2[f*144+k0]   : 0.f;
        float hi = (k0+1 < 144)? w2[f*144+k0+1] : 0.f;
        ws[OFF_W2P + w] = pk2(lo,hi);
    }
}

// ---------------- kF: 512 threads = 8 waves; wave-pair (tl,h) co-owns tile tl (F-dim split).
// grid 512, block = 4 tiles = 64 agents = 8 batches.
__global__ __launch_bounds__(512,4) void kF(const unsigned* __restrict__ ws,
        const float* __restrict__ xin, const float* __restrict__ pos,
        const float* __restrict__ oneh, const float* __restrict__ acts,
        const float* __restrict__ pols,
        const float* __restrict__ w1, const float* __restrict__ b1,
        const float* __restrict__ b2,
        const float* __restrict__ se_b,
        const float* __restrict__ sap_b, const float* __restrict__ av_b,
        const float* __restrict__ f1_b, const float* __restrict__ f2_w,
        const float* __restrict__ f2_b,
        float* __restrict__ wout, float* __restrict__ value){
    __shared__ unsigned SM[9216];     // conv overlay | AB: stage[4096] + U1[5120]
    __shared__ unsigned stPk[4096];   // state packs: A[4*512] | P[4*512]
    __shared__ unsigned sA64[2176];   // bf16 [64 rows][68]
    __shared__ unsigned sP64[2176];
    __shared__ float s_w[512];
    __shared__ float s_bias[384];     // sap_b | av_b | f1_b | f2_w
    __shared__ float s_ub[256];       // u | se_b
    const int t = threadIdx.x;
    const int wv = t>>6, lane = t&63;
    const int g = lane>>4, c = lane&15;
    const int tl = wv>>1, h = wv&1;

    // ===== conv overlay layout =====
    float* c_in   = (float*)SM;             // 2*1216 = 2432
    unsigned* hpk = SM + 2432;              // 4*1280 = 5120 (bf16 B-packs [16 ag][K=160])
    float* c_ap   = (float*)(SM+7552);      // 320
    float* c_pose = (float*)(SM+7872);      // 320
    float* c_w1   = (float*)(SM+8192);      // 432
    float* c_b1   = (float*)(SM+8624);      // 16
    float* c_b2   = (float*)(SM+8640);      // 32 (ends 8672 <= 9216)
    if (t<432) c_w1[t] = w1[t];
    else if (t<448) c_b1[t-432] = b1[t-432];
    else if (t<480) c_b2[t-448] = b2[t-448];
    hpk[(t>>7)*1280 + 1152 + (t&127)] = 0;   // zero K-pad 144..159 of all 4 packs
    if (t<384)
        s_bias[t] = (t<128)? sap_b[t] : (t<256)? av_b[t-128] : (t<320)? f1_b[t-256] : f2_w[t-320];
    if (t<256) s_ub[t] = (t<128)? ((const float*)ws)[OFF_U+t] : se_b[t-128];

    // ===== Phase C: conv encoder, 2 passes of 2 tiles =====
    for (int p=0; p<2; ++p){
        for (int q=t; q<2400; q+=512){
            int tp=q/1200, rr=q-tp*1200, ag=rr/75, r=rr-ag*75;
            size_t row = (size_t)blockIdx.x*64 + (p*2+tp)*16 + ag;
            c_in[tp*1216 + ag*76 + r] = xin[row*75 + r];
        }
        if (t<320){
            int tp=t/160, rr=t-tp*160, ag=rr/10, k=rr-ag*10;
            size_t row = (size_t)blockIdx.x*64 + (p*2+tp)*16 + ag;
            c_ap[t]   = (k<5)? acts[row*5+k] : pols[row*5+(k-5)];
            c_pose[t] = (k<2)? pos[row*2+k]  : oneh[row*8+(k-2)];
        }
        __syncthreads();
        // conv1: thread = (tp = t>>8, ag = t&15, oc = (t>>4)&15)
        {
            const int tp = t>>8, tt = t&255, ag = tt&15, oc = tt>>4;
            float w[27];
            #pragma unroll
            for (int i=0;i<27;++i) w[i]=c_w1[oc*27+i];
            float out[9];
            float bb = c_b1[oc];
            #pragma unroll
            for (int q=0;q<9;++q) out[q]=bb;
            #pragma unroll
            for (int ic=0;ic<3;++ic){
                float pin[25];
                #pragma unroll
                for (int i=0;i<25;++i) pin[i]=c_in[tp*1216 + ag*76 + ic*25 + i];
                #pragma unroll
                for (int y=0;y<3;++y)
                  #pragma unroll
                  for (int x=0;x<3;++x)
                    #pragma unroll
                    for (int ky=0;ky<3;++ky)
                      #pragma unroll
                      for (int kx=0;kx<3;++kx)
                        out[y*3+x] += pin[(y+ky)*5+(x+kx)] * w[ic*9+ky*3+kx];
            }
            unsigned short* hp16 = (unsigned short*)(hpk + (p*2+tp)*1280);
            #pragma unroll
            for (int q=0;q<9;++q){
                float v = out[q];
                v = (v>=0.f)? v : 0.01f*v;
                int k = oc*9+q;
                int word = (k>>3)*64 + ag*4 + ((k>>1)&3);
                hp16[word*2 + (k&1)] = (unsigned short)bfr(v);
            }
        }
        // pose/act/pol pack words (ft 4..7) -> stPk, 1 slot/thread
        {
            const int tp = t>>8, tt = t&255;
            const int ft4 = tt>>6, r = (tt>>2)&15, wi = tt&3;
            const int f0 = 32 + ft4*8 + wi*2;
            float a0=0.f,a1=0.f,p0=0.f,p1=0.f;
            if (f0 < 42){ a0 = c_pose[tp*160 + r*10 + f0-32]; p0 = a0; }
            else if (f0 < 47){ a0 = c_ap[tp*160 + r*10 + f0-42]; p0 = c_ap[tp*160 + r*10+5 + f0-42]; }
            if (f0+1 < 42){ a1 = c_pose[tp*160 + r*10 + f0-31]; p1 = a1; }
            else if (f0+1 < 47){ a1 = c_ap[tp*160 + r*10 + f0-41]; p1 = c_ap[tp*160 + r*10+5 + f0-41]; }
            int word = (p*2+tp)*512 + (4+ft4)*64 + r*4 + wi;
            stPk[word]      = pk2(a0,a1);
            stPk[2048+word] = pk2(p0,p1);
        }
        __syncthreads();
    }
    // conv2 as per-wave MFMA: waves 0..3 each consume one pack
    if (wv < 4){
        const unsigned* hw = hpk + wv*1280;
        f32x4 c2[2];
        c2[0] = (f32x4){0.f,0.f,0.f,0.f};
        c2[1] = (f32x4){0.f,0.f,0.f,0.f};
        #pragma unroll
        for (int kt=0; kt<5; ++kt){
            short8 hb  = fragld(hw + kt*256 + lane*4);
            short8 w0f = fragld(ws + OFF_W2P + kt*256 + lane*4);
            short8 w1f = fragld(ws + OFF_W2P + 1280 + kt*256 + lane*4);
            c2[0] = MFMA(w0f, hb, c2[0]);
            c2[1] = MFMA(w1f, hb, c2[1]);
        }
        #pragma unroll
        for (int ft=0; ft<2; ++ft){
            const float* bp = &c_b2[ft*16 + g*4];
            float d0 = c2[ft][0]+bp[0]; d0 = (d0>=0.f)? d0 : 0.01f*d0;
            float d1 = c2[ft][1]+bp[1]; d1 = (d1>=0.f)? d1 : 0.01f*d1;
            float d2 = c2[ft][2]+bp[2]; d2 = (d2>=0.f)? d2 : 0.01f*d2;
            float d3 = c2[ft][3]+bp[3]; d3 = (d3>=0.f)? d3 : 0.01f*d3;
            int word = wv*512 + (2*ft + (g>>1))*64 + c*4 + (g&1)*2;
            uint2 pw = make_uint2(pk2(d0,d1), pk2(d2,d3));
            *(uint2*)&stPk[word] = pw;
            *(uint2*)&stPk[2048+word] = pw;
        }
    }
    __syncthreads();   // conv regions die

    // ===== Phase AB =====
    const int tile = blockIdx.x*4 + tl;
    short8 bfA0 = fragld(&stPk[tl*512 + lane*4]);
    short8 bfA1 = fragld(&stPk[tl*512 + 256 + lane*4]);
    short8 bfP0 = fragld(&stPk[2048 + tl*512 + lane*4]);
    short8 bfP1 = fragld(&stPk[2048 + tl*512 + 256 + lane*4]);
    unsigned* stage = SM;                 // 4096-word pair buffer
    unsigned* U1 = SM + 4096;             // 5120
    unsigned* wS = U1 + tl*1280;          // per-tile 1024-word repack scratch (shared by wave pair)

    uint4 r0, r1;
#define PREFP(off) { r0 = *(const uint4*)(ws + (off) + t*4); \
                     r1 = *(const uint4*)(ws + (off) + 2048 + t*4); }
#define WRP() { *(uint4*)&stage[t*4] = r0; *(uint4*)&stage[2048 + t*4] = r1; }

    PREFP(OFF_SE);
    WRP();
    PREFP(OFF_M);
    __syncthreads();

    // ---- SE: wave h computes ftiles h*4+i ----
    f32x4 acc[4];
    #pragma unroll
    for (int i=0;i<4;++i) acc[i] = (f32x4){0.f,0.f,0.f,0.f};
    #pragma unroll
    for (int i=0;i<4;++i){
        short8 a0 = fragld(&stage[h*2048 + i*512 + lane*4]);
        short8 a1 = fragld(&stage[h*2048 + i*512 + 256 + lane*4]);
        acc[i] = MFMA(a0, bfA0, acc[i]);
        acc[i] = MFMA(a1, bfA1, acc[i]);
    }
    #pragma unroll
    for (int i=0;i<4;++i){
        int ft = h*4+i;
        const float* bp = &s_ub[128 + ft*16 + g*4];
        float d0 = fast_tanh(acc[i][0]+bp[0]);
        float d1 = fast_tanh(acc[i][1]+bp[1]);
        float d2 = fast_tanh(acc[i][2]+bp[2]);
        float d3 = fast_tanh(acc[i][3]+bp[3]);
        int word = (2*ft + (g>>1))*64 + c*4 + (g&1)*2;
        *(uint2*)&wS[word] = make_uint2(pk2(d0,d1), pk2(d2,d3));
    }
    __syncthreads();           // E complete; SE stage reads done
    short8 ef[4];
    #pragma unroll
    for (int kt=0; kt<4; ++kt) ef[kt] = fragld(&wS[kt*256 + lane*4]);
    __syncthreads();           // ef reads done -> wS free, stage free
    WRP();                     // M pair 0 (ftiles 0..3)
    PREFP(OFF_M + 4096);
    __syncthreads();
    // ---- M pair 0: wave h==0 computes T ftiles 0..3 ----
    if (h==0){
        #pragma unroll
        for (int fl=0; fl<4; ++fl){
            f32x4 a2 = (f32x4){0.f,0.f,0.f,0.f};
            #pragma unroll
            for (int kt=0; kt<4; ++kt)
                a2 = MFMA(fragld(&stage[fl*1024 + kt*256 + lane*4]), ef[kt], a2);
            const float* up = &s_ub[fl*16 + g*4];
            int word = (2*fl + (g>>1))*64 + c*4 + (g&1)*2;
            *(uint2*)&wS[word] = make_uint2(pk2(a2[0]+up[0], a2[1]+up[1]),
                                            pk2(a2[2]+up[2], a2[3]+up[3]));
        }
    }
    __syncthreads();
    WRP();                     // M pair 1 (ftiles 4..7)
    PREFP(OFF_SAP);
    __syncthreads();
    if (h==1){
        #pragma unroll
        for (int fl=0; fl<4; ++fl){
            int ft = 4+fl;
            f32x4 a2 = (f32x4){0.f,0.f,0.f,0.f};
            #pragma unroll
            for (int kt=0; kt<4; ++kt)
                a2 = MFMA(fragld(&stage[fl*1024 + kt*256 + lane*4]), ef[kt], a2);
            const float* up = &s_ub[ft*16 + g*4];
            int word = (2*ft + (g>>1))*64 + c*4 + (g&1)*2;
            *(uint2*)&wS[word] = make_uint2(pk2(a2[0]+up[0], a2[1]+up[1]),
                                            pk2(a2[2]+up[2], a2[3]+up[3]));
        }
    }
    __syncthreads();           // T complete; M stage reads done
    // ---- logits + softmax (both waves compute; h==0 writes) ----
    {
        f32x4 L = (f32x4){0.f,0.f,0.f,0.f};
        #pragma unroll
        for (int kt=0; kt<4; ++kt)
            L = MFMA(fragld(&wS[kt*256 + lane*4]), ef[kt], L);
        float sc[4];
        #pragma unroll
        for (int q=0;q<4;++q) sc[q] = L[q]*0.08838834764831845f;
        #pragma unroll
        for (int q=0;q<4;++q){
            float m = sc[q];
            m = fmaxf(m, __shfl_xor(m,1));
            m = fmaxf(m, __shfl_xor(m,2));
            m = fmaxf(m, __shfl_xor(m,4));
            float ex = __expf(sc[q]-m);
            float su = ex;
            su += __shfl_xor(su,1);
            su += __shfl_xor(su,2);
            su += __shfl_xor(su,4);
            sc[q] = ex/su;
        }
        if (h==0 && (c>>3) == (g>>1)){
            int lb = tl*2 + (g>>1);
            int batch = tile*2 + (g>>1);
            int idx = ((g&1)*4)*8 + (c&7);
            #pragma unroll
            for (int q=0;q<4;++q){
                float v = sc[q];
                wout[batch*64 + idx + q*8] = v;
                s_w[lb*64 + idx + q*8] = v;
            }
        }
    }
    __syncthreads();           // tf reads done -> wS free; stage free
    WRP();                     // SAP pair
    PREFP(OFF_AV);
    __syncthreads();
    // ---- SAP: wave h ftiles h*4+i, both variants ----
    f32x4 aS[2][4];
    #pragma unroll
    for (int v=0;v<2;++v)
      #pragma unroll
      for (int i=0;i<4;++i) aS[v][i] = (f32x4){0.f,0.f,0.f,0.f};
    #pragma unroll
    for (int i=0;i<4;++i){
        short8 a0 = fragld(&stage[h*2048 + i*512 + lane*4]);
        short8 a1 = fragld(&stage[h*2048 + i*512 + 256 + lane*4]);
        aS[0][i] = MFMA(a0, bfA0, aS[0][i]);
        aS[0][i] = MFMA(a1, bfA1, aS[0][i]);
        aS[1][i] = MFMA(a0, bfP0, aS[1][i]);
        aS[1][i] = MFMA(a1, bfP1, aS[1][i]);
    }
    short8 spA[4], spP[4];
    #pragma unroll
    for (int i=0;i<4;++i){
        int ft = h*4+i;
        const float* bp = &s_bias[ft*16 + g*4];
        float d0 = fast_tanh(aS[0][i][0]+bp[0]);
        float d1 = fast_tanh(aS[0][i][1]+bp[1]);
        float d2 = fast_tanh(aS[0][i][2]+bp[2]);
        float d3 = fast_tanh(aS[0][i][3]+bp[3]);
        int word = (2*ft + (g>>1))*64 + c*4 + (g&1)*2;
        *(uint2*)&wS[word] = make_uint2(pk2(d0,d1), pk2(d2,d3));
    }
    __syncthreads();
    #pragma unroll
    for (int kt=0; kt<4; ++kt) spA[kt] = fragld(&wS[kt*256 + lane*4]);
    __syncthreads();
    #pragma unroll
    for (int i=0;i<4;++i){
        int ft = h*4+i;
        const float* bp = &s_bias[ft*16 + g*4];
        float d0 = fast_tanh(aS[1][i][0]+bp[0]);
        float d1 = fast_tanh(aS[1][i][1]+bp[1]);
        float d2 = fast_tanh(aS[1][i][2]+bp[2]);
        float d3 = fast_tanh(aS[1][i][3]+bp[3]);
        int word = (2*ft + (g>>1))*64 + c*4 + (g&1)*2;
        *(uint2*)&wS[word] = make_uint2(pk2(d0,d1), pk2(d2,d3));
    }
    __syncthreads();
    #pragma unroll
    for (int kt=0; kt<4; ++kt) spP[kt] = fragld(&wS[kt*256 + lane*4]);
    __syncthreads();           // spP done; SAP stage reads done
    WRP();                     // AV pair 0 (ftiles 0..3)
    PREFP(OFF_AV + 4096);
    __syncthreads();
    // ---- AV: wave h takes ftiles {2h,2h+1} of each pair ----
    f32x4 aV[2][4];
    #pragma unroll
    for (int v=0;v<2;++v)
      #pragma unroll
      for (int i=0;i<4;++i) aV[v][i] = (f32x4){0.f,0.f,0.f,0.f};
    #pragma unroll
    for (int j=0;j<2;++j){
        int fl = 2*h + j;
        #pragma unroll
        for (int kt=0; kt<4; ++kt){
            short8 af = fragld(&stage[fl*1024 + kt*256 + lane*4]);
            aV[0][j] = MFMA(af, spA[kt], aV[0][j]);
            aV[1][j] = MFMA(af, spP[kt], aV[1][j]);
        }
    }
    __syncthreads();
    WRP();                     // AV pair 1 (ftiles 4..7)
    PREFP(OFF_F1);
    __syncthreads();
    #pragma unroll
    for (int j=0;j<2;++j){
        int fl = 2*h + j;
        #pragma unroll
        for (int kt=0; kt<4; ++kt){
            short8 af = fragld(&stage[fl*1024 + kt*256 + lane*4]);
            aV[0][2+j] = MFMA(af, spA[kt], aV[0][2+j]);
            aV[1][2+j] = MFMA(af, spP[kt], aV[1][2+j]);
        }
    }
    // AV build: wave h's global ftiles {2h,2h+1,4+2h,4+2h+1}
    short8 avA[4], avP[4];
    #pragma unroll
    for (int k=0;k<4;++k){
        int ft = (k>>1)*4 + 2*h + (k&1);
        const float* bp = &s_bias[128 + ft*16 + g*4];
        float d0 = fast_tanh(aV[0][k][0]+bp[0]);
        float d1 = fast_tanh(aV[0][k][1]+bp[1]);
        float d2 = fast_tanh(aV[0][k][2]+bp[2]);
        float d3 = fast_tanh(aV[0][k][3]+bp[3]);
        int word = (2*ft + (g>>1))*64 + c*4 + (g&1)*2;
        *(uint2*)&wS[word] = make_uint2(pk2(d0,d1), pk2(d2,d3));
    }
    __syncthreads();
    #pragma unroll
    for (int kt=0; kt<4; ++kt) avA[kt] = fragld(&wS[kt*256 + lane*4]);
    __syncthreads();
    #pragma unroll
    for (int k=0;k<4;++k){
        int ft = (k>>1)*4 + 2*h + (k&1);
        const float* bp = &s_bias[128 + ft*16 + g*4];
        float d0 = fast_tanh(aV[1][k][0]+bp[0]);
        float d1 = fast_tanh(aV[1][k][1]+bp[1]);
        float d2 = fast_tanh(aV[1][k][2]+bp[2]);
        float d3 = fast_tanh(aV[1][k][3]+bp[3]);
        int word = (2*ft + (g>>1))*64 + c*4 + (g&1)*2;
        *(uint2*)&wS[word] = make_uint2(pk2(d0,d1), pk2(d2,d3));
    }
    __syncthreads();
    #pragma unroll
    for (int kt=0; kt<4; ++kt) avP[kt] = fragld(&wS[kt*256 + lane*4]);
    __syncthreads();           // avP done; AV stage reads done
    WRP();                     // F1 pair (ftiles 0..3)
    __syncthreads();
    // ---- F1: wave h ftiles 2h, 2h+1 ----
    f32x4 aF[2][2];
    #pragma unroll
    for (int v=0;v<2;++v)
      #pragma unroll
      for (int j=0;j<2;++j) aF[v][j] = (f32x4){0.f,0.f,0.f,0.f};
    #pragma unroll
    for (int j=0;j<2;++j){
        int fl = 2*h + j;
        #pragma unroll
        for (int kt=0; kt<4; ++kt){
            short8 af = fragld(&stage[fl*1024 + kt*256 + lane*4]);
            aF[0][j] = MFMA(af, avA[kt], aF[0][j]);
            aF[1][j] = MFMA(af, avP[kt], aF[1][j]);
        }
    }
    {
        int row = tl*16 + c;
        #pragma unroll
        for (int v=0;v<2;++v){
            unsigned* dst = v? sP64 : sA64;
            #pragma unroll
            for (int j=0;j<2;++j){
                int ft = 2*h + j;
                int idx = row*34 + ft*8 + 2*g;
                *(uint2*)&dst[idx] = make_uint2(pk2(aF[v][j][0], aF[v][j][1]),
                                                pk2(aF[v][j][2], aF[v][j][3]));
            }
        }
    }
    __syncthreads();
    // ---- tail: b64 + final mix ----
    float* s_b64 = (float*)U1;  // [64 rows][68]
    const unsigned short* A16 = (const unsigned short*)sA64;
    const unsigned short* P16 = (const unsigned short*)sP64;
    #pragma unroll
    for (int k=0; k<8; ++k){
        int e = t + 512*k;
        int bq = e>>9, a = (e>>6)&7, cc = e&63;
        const float* wp = &s_w[bq*64 + a*8];
        float acc4 = 0.f;
        #pragma unroll
        for (int j=0;j<8;++j) acc4 += wp[j]*bf2f(A16[(bq*8+j)*68 + cc]);
        s_b64[(bq*8+a)*68 + cc] = acc4;
    }
    __syncthreads();
    {
        int bq = t>>6, a = (t>>3)&7, i = t&7;
        float w_ai = s_w[bq*64 + a*8 + i];
        const float* pb = &s_b64[(bq*8+a)*68];
        const unsigned short* pA = &A16[(bq*8+i)*68];
        const unsigned short* pP = &P16[(bq*8+i)*68];
        float acc5 = 0.f;
        #pragma unroll 8
        for (int cc=0; cc<64; ++cc){
            float dd = bf2f(pP[cc]) - bf2f(pA[cc]);
            acc5 += fast_tanh(pb[cc] + w_ai*dd + s_bias[256+cc]) * s_bias[320+cc];
        }
        value[(size_t)blockIdx.x*512 + t] = acc5 + f2_b[0];
    }
#undef PREFP
#undef WRP
}

extern "C" void kernel_launch(void* const* d_in, const int* in_sizes, int n_in,
                              void* d_out, int out_size, void* d_ws, size_t ws_size,
                              hipStream_t stream){
    const float* agent_states = (const float*)d_in[0];
    const float* pos    = (const float*)d_in[1];
    const float* oneh   = (const float*)d_in[2];
    const float* pols   = (const float*)d_in[3];
    const float* acts   = (const float*)d_in[4];
    const float* w1     = (const float*)d_in[5];
    const float* b1     = (const float*)d_in[6];
    const float* w2     = (const float*)d_in[7];
    const float* b2     = (const float*)d_in[8];
    const float* se_w   = (const float*)d_in[9];
    const float* se_b   = (const float*)d_in[10];
    const float* key_w  = (const float*)d_in[11];
    const float* query_w= (const float*)d_in[13];
    const float* query_b= (const float*)d_in[14];
    const float* sap_w  = (const float*)d_in[15];
    const float* sap_b  = (const float*)d_in[16];
    const float* av_w   = (const float*)d_in[17];
    const float* av_b   = (const float*)d_in[18];
    const float* f1_w   = (const float*)d_in[19];
    const float* f1_b   = (const float*)d_in[20];
    const float* f2_w   = (const float*)d_in[21];
    const float* f2_b   = (const float*)d_in[22];

    unsigned* ws = (unsigned*)d_ws;

    float* value = (float*)d_out;
    float* wout  = value + (size_t)NB*NA*NA;

    kW<<<123, 256, 0, stream>>>(se_w, sap_w, av_w, f1_w, query_w, key_w, query_b, w2, ws);
    kF<<<BN/64, 512, 0, stream>>>(ws, agent_states, pos, oneh, acts, pols,
                                  w1, b1, b2, se_b, sap_b, av_b, f1_b, f2_w, f2_b,
                                  wout, value);
}

// Round 12
// 53.879 us; speedup vs baseline: 1.1137x; 1.1137x over previous
//
#include <hip/hip_runtime.h>
#include <math.h>

#define NB 4096
#define NA 8
#define BN (NB*NA)   // 32768

// ws layout (u32 words)
#define OFF_SE   0            // se pack:  8 tiles * 512
#define OFF_SAP  4096         // sap pack: 8 tiles * 512
#define OFF_AV   8192         // av pack:  8 tiles * 1024
#define OFF_F1   16384        // f1 pack:  4 tiles * 1024
#define OFF_M    20480        // M pack:   8 tiles * 1024
#define OFF_U    28672        // u: 128 floats
#define OFF_W2P  28800        // conv2 weight A-frag pack: 2 ftiles * 1280 (K=160 pad)
// ws end: 31360 words

typedef short short8 __attribute__((ext_vector_type(8)));
typedef float f32x4 __attribute__((ext_vector_type(4)));

#define MFMA(a,b,c) __builtin_amdgcn_mfma_f32_16x16x32_bf16(a,b,c,0,0,0)

__device__ __forceinline__ float fast_tanh(float x){
    float e = __expf(2.0f*x);
    return 1.0f - 2.0f*__builtin_amdgcn_rcpf(e+1.0f);
}
__device__ __forceinline__ unsigned bfr(float x){
    unsigned u = __float_as_uint(x);
    return (u + 0x7fffu + ((u>>16)&1u)) >> 16;
}
__device__ __forceinline__ unsigned pk2(float lo, float hi){
    return bfr(lo) | (bfr(hi)<<16);
}
__device__ __forceinline__ float bf2f(unsigned short s){
    return __uint_as_float(((unsigned)s)<<16);
}
__device__ __forceinline__ short8 fragld(const unsigned* p){
    union { uint4 u; short8 s; } cv;
    cv.u = *(const uint4*)p;
    return cv.s;
}

// ---------------- kW: pack all weights as A-fragments (pack16 of W^T), compute M, u, w2 pack
__global__ __launch_bounds__(256) void kW(const float* __restrict__ se_w,
        const float* __restrict__ sap_w, const float* __restrict__ av_w,
        const float* __restrict__ f1_w, const float* __restrict__ qw,
        const float* __restrict__ kw, const float* __restrict__ qb,
        const float* __restrict__ w2,
        unsigned* __restrict__ ws){
    int idx = blockIdx.x*256 + threadIdx.x;
    if (idx < 4096){                       // sePk (F=64 pad, rows f2=128)
        int w = idx, tile = w>>9, rem = w&511;
        int ft = rem>>6, r2 = (rem>>2)&15, wi = rem&3;
        int f2 = tile*16 + r2, f1 = ft*8 + wi*2;
        float lo = (f1   < 42)? se_w[f1*128+f2]     : 0.f;
        float hi = (f1+1 < 42)? se_w[(f1+1)*128+f2] : 0.f;
        ws[OFF_SE + w] = pk2(lo,hi);
    } else if (idx < 8192){                // sapPk (F=64 pad, limit 47)
        int w = idx-4096, tile = w>>9, rem = w&511;
        int ft = rem>>6, r2 = (rem>>2)&15, wi = rem&3;
        int f2 = tile*16 + r2, f1 = ft*8 + wi*2;
        float lo = (f1   < 47)? sap_w[f1*128+f2]     : 0.f;
        float hi = (f1+1 < 47)? sap_w[(f1+1)*128+f2] : 0.f;
        ws[OFF_SAP + w] = pk2(lo,hi);
    } else if (idx < 16384){               // avPk (F=128)
        int w = idx-8192, tile = w>>10, rem = w&1023;
        int ft = rem>>6, r2 = (rem>>2)&15, wi = rem&3;
        int f2 = tile*16 + r2, f1 = ft*8 + wi*2;
        ws[OFF_AV + w] = pk2(av_w[f1*128+f2], av_w[(f1+1)*128+f2]);
    } else if (idx < 20480){               // f1Pk (F=128, rows f2=64)
        int w = idx-16384, tile = w>>10, rem = w&1023;
        int ft = rem>>6, r2 = (rem>>2)&15, wi = rem&3;
        int f2 = tile*16 + r2, f1 = ft*8 + wi*2;
        ws[OFF_F1 + w] = pk2(f1_w[f1*64+f2], f1_w[(f1+1)*64+f2]);
    } else if (idx < 28672){               // MPk: M[e][f2] = qw[e]·kw[f2]
        int w = idx-20480, tile = w>>10, rem = w&1023;
        int ft = rem>>6, r2 = (rem>>2)&15, wi = rem&3;
        int f2 = tile*16 + r2, e0 = ft*8 + wi*2;
        float lo=0.f, hi=0.f;
        for (int d=0; d<128; ++d){
            float kv = kw[f2*128+d];
            lo += qw[e0*128+d]*kv;
            hi += qw[(e0+1)*128+d]*kv;
        }
        ws[OFF_M + w] = pk2(lo,hi);
    } else if (idx < 28800){               // u[f] = qb·kw[f]
        int f = idx-28672;
        float a = 0.f;
        for (int d=0; d<128; ++d) a += qb[d]*kw[f*128+d];
        ((float*)ws)[OFF_U + f] = a;
    } else if (idx < 31360){               // conv2 weight A-frags: F=32, K=160 (pad from 144)
        int w = idx-28800;
        int ftile = w/1280, rem = w - ftile*1280;
        int ft = rem>>6, r2 = (rem>>2)&15, wi = rem&3;
        int f = ftile*16 + r2, k0 = ft*8 + wi*2;
        float lo = (k0   < 144)? w2[f*144+k0]   : 0.f;
        float hi = (k0+1 < 144)? w2[f*144+k0+1] : 0.f;
        ws[OFF_W2P + w] = pk2(lo,hi);
    }
}

// ---------------- kF: 2-tile blocks (128 threads = 2 waves, wave = tile). grid 1024.
// LDS 40448 B -> 4 blocks/CU. Same per-wave pipeline as the 52.4us round-10 kernel.
__global__ __launch_bounds__(128,2) void kF(const unsigned* __restrict__ ws,
        const float* __restrict__ xin, const float* __restrict__ pos,
        const float* __restrict__ oneh, const float* __restrict__ acts,
        const float* __restrict__ pols,
        const float* __restrict__ w1, const float* __restrict__ b1,
        const float* __restrict__ b2,
        const float* __restrict__ se_b,
        const float* __restrict__ sap_b, const float* __restrict__ av_b,
        const float* __restrict__ f1_b, const float* __restrict__ f2_w,
        const float* __restrict__ f2_b,
        float* __restrict__ wout, float* __restrict__ value){
    __shared__ unsigned SM[6144];     // conv overlay | AB: stage[2][2048] + U1[2048] ; tail: s_b64
    __shared__ unsigned stPkA[1024];  // A-state packs: 2 tiles * 512
    __shared__ unsigned stP5[128];    // P-diff (k-octet 5) words: 2 tiles * 64
    __shared__ unsigned sA64[1088];   // bf16 [32 rows][68]; head doubles as u|se_b park
    __shared__ unsigned sP64[1088];
    __shared__ float s_w[256];        // weight for 4 batches
    __shared__ float s_bias[384];     // sap_b | av_b | f1_b | f2_w
    const int t = threadIdx.x;
    const int wv = t>>6, lane = t&63;
    const int g = lane>>4, c = lane&15;

    // u | se_b parked in sA64 (dead until F1 writes it)
    float* s_ub = (float*)sA64;
    // ===== conv overlay =====
    float* c_in   = (float*)SM;             // 2432 words (2 tiles * 16 ag * 76)
    unsigned* hpk = SM + 2432;              // 2 packs * 1280 (bf16 B-packs [16 ag][K=160])
    float* c_ap   = (float*)(SM+4992);      // 320
    float* c_pose = (float*)(SM+5312);      // 320
    float* c_w1   = (float*)(SM+5632);      // 432
    float* c_b1   = (float*)(SM+6064);      // 16
    float* c_b2   = (float*)(SM+6080);      // 32 (ends 6112 <= 6144)
    for (int q=t; q<432; q+=128) c_w1[q] = w1[q];
    if (t<16) c_b1[t] = b1[t];
    else if (t<48) c_b2[t-16] = b2[t-16];
    for (int q=t; q<256; q+=128) hpk[(q>>7)*1280 + 1152 + (q&127)] = 0;   // zero K-pad
    for (int q=t; q<384; q+=128)
        s_bias[q] = (q<128)? sap_b[q] : (q<256)? av_b[q-128] : (q<320)? f1_b[q-256] : f2_w[q-320];
    for (int q=t; q<256; q+=128) s_ub[q] = (q<128)? ((const float*)ws)[OFF_U+q] : se_b[q-128];

    // ===== Phase C: conv encoder (one pass, 2 tiles) =====
    for (int q=t; q<2400; q+=128){
        int tp=q/1200, rr=q-tp*1200, ag=rr/75, r=rr-ag*75;
        c_in[tp*1216 + ag*76 + r] = xin[((size_t)blockIdx.x*32 + tp*16 + ag)*75 + r];
    }
    for (int q=t; q<320; q+=128){
        int tp=q/160, rr=q-tp*160, ag=rr/10, k=rr-ag*10;
        size_t row = (size_t)blockIdx.x*32 + tp*16 + ag;
        c_ap[q]   = (k<5)? acts[row*5+k] : pols[row*5+(k-5)];
        c_pose[q] = (k<2)? pos[row*2+k]  : oneh[row*8+(k-2)];
    }
    __syncthreads();
    // conv1: thread = (ag = t&15, oc base = t>>4); 4 subtasks (2 tiles x 2 oc-halves)
    #pragma unroll
    for (int tp=0; tp<2; ++tp){
        #pragma unroll
        for (int oh=0; oh<2; ++oh){
            const int ag = t&15, oc = (t>>4) + oh*8;
            float w[27];
            #pragma unroll
            for (int i=0;i<27;++i) w[i]=c_w1[oc*27+i];
            float out[9];
            float bb = c_b1[oc];
            #pragma unroll
            for (int q=0;q<9;++q) out[q]=bb;
            #pragma unroll
            for (int ic=0;ic<3;++ic){
                float pin[25];
                #pragma unroll
                for (int i=0;i<25;++i) pin[i]=c_in[tp*1216 + ag*76 + ic*25 + i];
                #pragma unroll
                for (int y=0;y<3;++y)
                  #pragma unroll
                  for (int x=0;x<3;++x)
                    #pragma unroll
                    for (int ky=0;ky<3;++ky)
                      #pragma unroll
                      for (int kx=0;kx<3;++kx)
                        out[y*3+x] += pin[(y+ky)*5+(x+kx)] * w[ic*9+ky*3+kx];
            }
            unsigned short* hp16 = (unsigned short*)(hpk + tp*1280);
            #pragma unroll
            for (int q=0;q<9;++q){
                float v = out[q];
                v = (v>=0.f)? v : 0.01f*v;
                int k = oc*9+q;
                int word = (k>>3)*64 + ag*4 + ((k>>1)&3);
                hp16[word*2 + (k&1)] = (unsigned short)bfr(v);
            }
        }
    }
    // pose/act/pol pack words (ft 4..7) -> stPkA; P-diff (ft4==1 octet) -> stP5
    for (int q=t; q<512; q+=128){
        const int tp = q>>8, tt = q&255;
        const int ft4 = tt>>6, r = (tt>>2)&15, wi = tt&3;
        const int f0 = 32 + ft4*8 + wi*2;
        float a0=0.f,a1=0.f,p0=0.f,p1=0.f;
        if (f0 < 42){ a0 = c_pose[tp*160 + r*10 + f0-32]; p0 = a0; }
        else if (f0 < 47){ a0 = c_ap[tp*160 + r*10 + f0-42]; p0 = c_ap[tp*160 + r*10+5 + f0-42]; }
        if (f0+1 < 42){ a1 = c_pose[tp*160 + r*10 + f0-31]; p1 = a1; }
        else if (f0+1 < 47){ a1 = c_ap[tp*160 + r*10 + f0-41]; p1 = c_ap[tp*160 + r*10+5 + f0-41]; }
        stPkA[tp*512 + (4+ft4)*64 + r*4 + wi] = pk2(a0,a1);
        if (ft4 == 1) stP5[tp*64 + r*4 + wi] = pk2(p0,p1);
    }
    __syncthreads();
    // conv2 as per-wave MFMA: wave wv consumes pack wv ([16 ag] x [32 oc] x K=160)
    {
        const unsigned* hw = hpk + wv*1280;
        f32x4 c2[2];
        c2[0] = (f32x4){0.f,0.f,0.f,0.f};
        c2[1] = (f32x4){0.f,0.f,0.f,0.f};
        #pragma unroll
        for (int kt=0; kt<5; ++kt){
            short8 hb  = fragld(hw + kt*256 + lane*4);
            short8 w0f = fragld(ws + OFF_W2P + kt*256 + lane*4);
            short8 w1f = fragld(ws + OFF_W2P + 1280 + kt*256 + lane*4);
            c2[0] = MFMA(w0f, hb, c2[0]);
            c2[1] = MFMA(w1f, hb, c2[1]);
        }
        #pragma unroll
        for (int ft=0; ft<2; ++ft){
            const float* bp = &c_b2[ft*16 + g*4];
            float d0 = c2[ft][0]+bp[0]; d0 = (d0>=0.f)? d0 : 0.01f*d0;
            float d1 = c2[ft][1]+bp[1]; d1 = (d1>=0.f)? d1 : 0.01f*d1;
            float d2 = c2[ft][2]+bp[2]; d2 = (d2>=0.f)? d2 : 0.01f*d2;
            float d3 = c2[ft][3]+bp[3]; d3 = (d3>=0.f)? d3 : 0.01f*d3;
            int word = wv*512 + (2*ft + (g>>1))*64 + c*4 + (g&1)*2;
            *(uint2*)&stPkA[word] = make_uint2(pk2(d0,d1), pk2(d2,d3));
        }
    }
    __syncthreads();   // conv regions die; SM becomes AB stage/scratch

    // ===== Phase AB (per-wave pipeline identical to round 10) =====
    const int tile = blockIdx.x*2 + wv;
    short8 bfA0 = fragld(&stPkA[wv*512 + lane*4]);
    short8 bfA1 = fragld(&stPkA[wv*512 + 256 + lane*4]);
    short8 bfP0 = bfA0;   // kt=0 identical
    const unsigned* p1addr = (g==1) ? &stP5[wv*64 + c*4]
                                    : &stPkA[wv*512 + 256 + lane*4];
    short8 bfP1 = fragld(p1addr);
    unsigned (*s_stage)[2048] = (unsigned (*)[2048])&SM[0];
    unsigned* U1 = &SM[4096];
    unsigned* wS = &U1[wv*1024];          // per-wave repack scratch (E/SAP/AV), 1024 words
    unsigned* tS = wS;                    // T scratch overlaps (E dead once ef[] cached)

    uint4 r0, r1;
#define PREF(off) { r0 = *(const uint4*)(ws + (off) + t*4); \
                    r1 = *(const uint4*)(ws + (off) + 512 + t*4); \
                    *(uint4*)&r0; }
#undef PREF
    uint4 r2, r3;
#define PREF(off) { r0 = *(const uint4*)(ws + (off) + t*4); \
                    r1 = *(const uint4*)(ws + (off) + 512 + t*4); \
                    r2 = *(const uint4*)(ws + (off) + 1024 + t*4); \
                    r3 = *(const uint4*)(ws + (off) + 1536 + t*4); }
#define WR(b) { *(uint4*)&s_stage[b][t*4] = r0; *(uint4*)&s_stage[b][512 + t*4] = r1; \
                *(uint4*)&s_stage[b][1024 + t*4] = r2; *(uint4*)&s_stage[b][1536 + t*4] = r3; }

    PREF(OFF_SE); WR(0);
    __syncthreads();

    // ---- SE chunks c0,c1 -> acc[8] ----
    f32x4 acc[8];
    #pragma unroll
    for (int i=0;i<8;++i) acc[i] = (f32x4){0.f,0.f,0.f,0.f};
    PREF(OFF_SE + 2048);
    #pragma unroll
    for (int ft=0; ft<4; ++ft){
        short8 a0 = fragld(&s_stage[0][ft*512 + lane*4]);
        short8 a1 = fragld(&s_stage[0][ft*512 + 256 + lane*4]);
        acc[ft] = MFMA(a0, bfA0, acc[ft]);
        acc[ft] = MFMA(a1, bfA1, acc[ft]);
    }
    WR(1); __syncthreads();
    PREF(OFF_M);
    #pragma unroll
    for (int ft=4; ft<8; ++ft){
        short8 a0 = fragld(&s_stage[1][(ft-4)*512 + lane*4]);
        short8 a1 = fragld(&s_stage[1][(ft-4)*512 + 256 + lane*4]);
        acc[ft] = MFMA(a0, bfA0, acc[ft]);
        acc[ft] = MFMA(a1, bfA1, acc[ft]);
    }
    WR(0);
    // E build -> wS, cache ef[4]
    #pragma unroll
    for (int ft=0; ft<8; ++ft){
        const float* bp = &s_ub[128 + ft*16 + g*4];
        float d0 = fast_tanh(acc[ft][0]+bp[0]);
        float d1 = fast_tanh(acc[ft][1]+bp[1]);
        float d2 = fast_tanh(acc[ft][2]+bp[2]);
        float d3 = fast_tanh(acc[ft][3]+bp[3]);
        int word = (2*ft + (g>>1))*64 + c*4 + (g&1)*2;
        *(uint2*)&wS[word] = make_uint2(pk2(d0,d1), pk2(d2,d3));
    }
    short8 ef[4];
    #pragma unroll
    for (int kt=0; kt<4; ++kt) ef[kt] = fragld(&wS[kt*256 + lane*4]);
    __syncthreads();

    // ---- M chunks c2..c5, fused T-write + logits ----
    f32x4 L = (f32x4){0.f,0.f,0.f,0.f};
    #pragma unroll
    for (int i=0; i<4; ++i){
        const int nextOff = (i<3)? (OFF_M + (i+1)*2048) : OFF_SAP;
        PREF(nextOff);
        f32x4 a2[2];
        a2[0] = (f32x4){0.f,0.f,0.f,0.f};
        a2[1] = (f32x4){0.f,0.f,0.f,0.f};
        #pragma unroll
        for (int ftl=0; ftl<2; ++ftl)
          #pragma unroll
          for (int kt=0; kt<4; ++kt){
            short8 mf = fragld(&s_stage[i&1][ftl*1024 + kt*256 + lane*4]);
            a2[ftl] = MFMA(mf, ef[kt], a2[ftl]);
          }
        WR((i+1)&1);
        #pragma unroll
        for (int ftl=0; ftl<2; ++ftl){
            const float* up = &s_ub[(2*i+ftl)*16 + g*4];
            int word = (2*ftl + (g>>1))*64 + c*4 + (g&1)*2;
            *(uint2*)&tS[word] = make_uint2(pk2(a2[ftl][0]+up[0], a2[ftl][1]+up[1]),
                                            pk2(a2[ftl][2]+up[2], a2[ftl][3]+up[3]));
        }
        short8 tf = fragld(&tS[lane*4]);
        L = MFMA(tf, ef[i], L);
        __syncthreads();
    }
    // softmax -> s_w + wout
    {
        float sc[4];
        #pragma unroll
        for (int q=0;q<4;++q) sc[q] = L[q]*0.08838834764831845f;
        #pragma unroll
        for (int q=0;q<4;++q){
            float m = sc[q];
            m = fmaxf(m, __shfl_xor(m,1));
            m = fmaxf(m, __shfl_xor(m,2));
            m = fmaxf(m, __shfl_xor(m,4));
            float ex = __expf(sc[q]-m);
            float su = ex;
            su += __shfl_xor(su,1);
            su += __shfl_xor(su,2);
            su += __shfl_xor(su,4);
            sc[q] = ex/su;
        }
        if ((c>>3) == (g>>1)){
            int lb = wv*2 + (g>>1);
            int batch = tile*2 + (g>>1);
            int idx = ((g&1)*4)*8 + (c&7);
            #pragma unroll
            for (int q=0;q<4;++q){
                float v = sc[q];
                wout[batch*64 + idx + q*8] = v;
                s_w[lb*64 + idx + q*8] = v;
            }
        }
    }

    // ---- SAP chunks c6,c7 -> aS[2][8] ----
    f32x4 aS[2][8];
    #pragma unroll
    for (int v=0;v<2;++v)
      #pragma unroll
      for (int i=0;i<8;++i) aS[v][i] = (f32x4){0.f,0.f,0.f,0.f};
    PREF(OFF_SAP + 2048);
    #pragma unroll
    for (int ft=0; ft<4; ++ft){
        short8 a0 = fragld(&s_stage[0][ft*512 + lane*4]);
        short8 a1 = fragld(&s_stage[0][ft*512 + 256 + lane*4]);
        aS[0][ft] = MFMA(a0, bfA0, aS[0][ft]);
        aS[0][ft] = MFMA(a1, bfA1, aS[0][ft]);
        aS[1][ft] = MFMA(a0, bfP0, aS[1][ft]);
        aS[1][ft] = MFMA(a1, bfP1, aS[1][ft]);
    }
    WR(1); __syncthreads();
    PREF(OFF_AV);
    #pragma unroll
    for (int ft=4; ft<8; ++ft){
        short8 a0 = fragld(&s_stage[1][(ft-4)*512 + lane*4]);
        short8 a1 = fragld(&s_stage[1][(ft-4)*512 + 256 + lane*4]);
        aS[0][ft] = MFMA(a0, bfA0, aS[0][ft]);
        aS[0][ft] = MFMA(a1, bfA1, aS[0][ft]);
        aS[1][ft] = MFMA(a0, bfP0, aS[1][ft]);
        aS[1][ft] = MFMA(a1, bfP1, aS[1][ft]);
    }
    WR(0);
    // SAP build (variant A then P through the wave-private scratch), cache frags
    short8 spA[4], spP[4];
    #pragma unroll
    for (int ft=0; ft<8; ++ft){
        const float* bp = &s_bias[ft*16 + g*4];
        float d0 = fast_tanh(aS[0][ft][0]+bp[0]);
        float d1 = fast_tanh(aS[0][ft][1]+bp[1]);
        float d2 = fast_tanh(aS[0][ft][2]+bp[2]);
        float d3 = fast_tanh(aS[0][ft][3]+bp[3]);
        int word = (2*ft + (g>>1))*64 + c*4 + (g&1)*2;
        *(uint2*)&wS[word] = make_uint2(pk2(d0,d1), pk2(d2,d3));
    }
    #pragma unroll
    for (int kt=0; kt<4; ++kt) spA[kt] = fragld(&wS[kt*256 + lane*4]);
    #pragma unroll
    for (int ft=0; ft<8; ++ft){
        const float* bp = &s_bias[ft*16 + g*4];
        float d0 = fast_tanh(aS[1][ft][0]+bp[0]);
        float d1 = fast_tanh(aS[1][ft][1]+bp[1]);
        float d2 = fast_tanh(aS[1][ft][2]+bp[2]);
        float d3 = fast_tanh(aS[1][ft][3]+bp[3]);
        int word = (2*ft + (g>>1))*64 + c*4 + (g&1)*2;
        *(uint2*)&wS[word] = make_uint2(pk2(d0,d1), pk2(d2,d3));
    }
    #pragma unroll
    for (int kt=0; kt<4; ++kt) spP[kt] = fragld(&wS[kt*256 + lane*4]);
    __syncthreads();

    // ---- AV chunks c8..c11 -> aV[2][8] ----
    f32x4 aV[2][8];
    #pragma unroll
    for (int v=0;v<2;++v)
      #pragma unroll
      for (int i=0;i<8;++i) aV[v][i] = (f32x4){0.f,0.f,0.f,0.f};
    short8 avA[4], avP[4];
    #pragma unroll
    for (int i=0; i<4; ++i){
        const int nextOff = (i<3)? (OFF_AV + (i+1)*2048) : OFF_F1;
        PREF(nextOff);
        #pragma unroll
        for (int ftl=0; ftl<2; ++ftl){
            const int ft = 2*i + ftl;
            #pragma unroll
            for (int kt=0; kt<4; ++kt){
                short8 af = fragld(&s_stage[i&1][ftl*1024 + kt*256 + lane*4]);
                aV[0][ft] = MFMA(af, spA[kt], aV[0][ft]);
                aV[1][ft] = MFMA(af, spP[kt], aV[1][ft]);
            }
        }
        WR((i+1)&1);
        if (i==3){
            // AV build (A then P through scratch), cache frags
            #pragma unroll
            for (int ft=0; ft<8; ++ft){
                const float* bp = &s_bias[128 + ft*16 + g*4];
                float d0 = fast_tanh(aV[0][ft][0]+bp[0]);
                float d1 = fast_tanh(aV[0][ft][1]+bp[1]);
                float d2 = fast_tanh(aV[0][ft][2]+bp[2]);
                float d3 = fast_tanh(aV[0][ft][3]+bp[3]);
                int word = (2*ft + (g>>1))*64 + c*4 + (g&1)*2;
                *(uint2*)&wS[word] = make_uint2(pk2(d0,d1), pk2(d2,d3));
            }
            #pragma unroll
            for (int kt=0; kt<4; ++kt) avA[kt] = fragld(&wS[kt*256 + lane*4]);
            #pragma unroll
            for (int ft=0; ft<8; ++ft){
                const float* bp = &s_bias[128 + ft*16 + g*4];
                float d0 = fast_tanh(aV[1][ft][0]+bp[0]);
                float d1 = fast_tanh(aV[1][ft][1]+bp[1]);
                float d2 = fast_tanh(aV[1][ft][2]+bp[2]);
                float d3 = fast_tanh(aV[1][ft][3]+bp[3]);
                int word = (2*ft + (g>>1))*64 + c*4 + (g&1)*2;
                *(uint2*)&wS[word] = make_uint2(pk2(d0,d1), pk2(d2,d3));
            }
            #pragma unroll
            for (int kt=0; kt<4; ++kt) avP[kt] = fragld(&wS[kt*256 + lane*4]);
        }
        __syncthreads();
    }

    // ---- F1 chunks c12,c13 -> aF[2][4] ----
    f32x4 aF[2][4];
    #pragma unroll
    for (int v=0;v<2;++v)
      #pragma unroll
      for (int i=0;i<4;++i) aF[v][i] = (f32x4){0.f,0.f,0.f,0.f};
    PREF(OFF_F1 + 2048);
    #pragma unroll
    for (int ftl=0; ftl<2; ++ftl)
      #pragma unroll
      for (int kt=0; kt<4; ++kt){
        short8 af = fragld(&s_stage[0][ftl*1024 + kt*256 + lane*4]);
        aF[0][ftl] = MFMA(af, avA[kt], aF[0][ftl]);
        aF[1][ftl] = MFMA(af, avP[kt], aF[1][ftl]);
      }
    WR(1); __syncthreads();
    #pragma unroll
    for (int ftl=0; ftl<2; ++ftl)
      #pragma unroll
      for (int kt=0; kt<4; ++kt){
        short8 af = fragld(&s_stage[1][ftl*1024 + kt*256 + lane*4]);
        aF[0][2+ftl] = MFMA(af, avA[kt], aF[0][2+ftl]);
        aF[1][2+ftl] = MFMA(af, avP[kt], aF[1][2+ftl]);
      }
    {
        int row = wv*16 + c;
        #pragma unroll
        for (int v=0;v<2;++v){
            unsigned* dst = v? sP64 : sA64;
            #pragma unroll
            for (int ft=0; ft<4; ++ft){
                int idx = row*34 + ft*8 + 2*g;
                *(uint2*)&dst[idx] = make_uint2(pk2(aF[v][ft][0], aF[v][ft][1]),
                                                pk2(aF[v][ft][2], aF[v][ft][3]));
            }
        }
    }
    __syncthreads();
    // ---- tail: b64 (in stage overlay) + final mix ----
    float* s_b64 = (float*)SM;  // [32 rows][68] floats = 2176 words <= 6144
    const unsigned short* A16 = (const unsigned short*)sA64;
    const unsigned short* P16 = (const unsigned short*)sP64;
    #pragma unroll
    for (int k=0; k<16; ++k){
        int e = t + 128*k;
        int bq = e>>9, a = (e>>6)&7, cc = e&63;
        const float* wp = &s_w[bq*64 + a*8];
        float acc4 = 0.f;
        #pragma unroll
        for (int j=0;j<8;++j) acc4 += wp[j]*bf2f(A16[(bq*8+j)*68 + cc]);
        s_b64[(bq*8+a)*68 + cc] = acc4;
    }
    __syncthreads();
    #pragma unroll
    for (int k=0; k<2; ++k){
        int o = t + 128*k;
        int bq = o>>6, a = (o>>3)&7, i = o&7;
        float w_ai = s_w[bq*64 + a*8 + i];
        const float* pb = &s_b64[(bq*8+a)*68];
        const unsigned short* pA = &A16[(bq*8+i)*68];
        const unsigned short* pP = &P16[(bq*8+i)*68];
        float acc5 = 0.f;
        #pragma unroll 8
        for (int cc=0; cc<64; ++cc){
            float dd = bf2f(pP[cc]) - bf2f(pA[cc]);
            acc5 += fast_tanh(pb[cc] + w_ai*dd + s_bias[256+cc]) * s_bias[320+cc];
        }
        value[(size_t)blockIdx.x*256 + o] = acc5 + f2_b[0];
    }
#undef PREF
#undef WR
}

extern "C" void kernel_launch(void* const* d_in, const int* in_sizes, int n_in,
                              void* d_out, int out_size, void* d_ws, size_t ws_size,
                              hipStream_t stream){
    const float* agent_states = (const float*)d_in[0];
    const float* pos    = (const float*)d_in[1];
    const float* oneh   = (const float*)d_in[2];
    const float* pols   = (const float*)d_in[3];
    const float* acts   = (const float*)d_in[4];
    const float* w1     = (const float*)d_in[5];
    const float* b1     = (const float*)d_in[6];
    const float* w2     = (const float*)d_in[7];
    const float* b2     = (const float*)d_in[8];
    const float* se_w   = (const float*)d_in[9];
    const float* se_b   = (const float*)d_in[10];
    const float* key_w  = (const float*)d_in[11];
    const float* query_w= (const float*)d_in[13];
    const float* query_b= (const float*)d_in[14];
    const float* sap_w  = (const float*)d_in[15];
    const float* sap_b  = (const float*)d_in[16];
    const float* av_w   = (const float*)d_in[17];
    const float* av_b   = (const float*)d_in[18];
    const float* f1_w   = (const float*)d_in[19];
    const float* f1_b   = (const float*)d_in[20];
    const float* f2_w   = (const float*)d_in[21];
    const float* f2_b   = (const float*)d_in[22];

    unsigned* ws = (unsigned*)d_ws;

    float* value = (float*)d_out;
    float* wout  = value + (size_t)NB*NA*NA;

    kW<<<123, 256, 0, stream>>>(se_w, sap_w, av_w, f1_w, query_w, key_w, query_b, w2, ws);
    kF<<<BN/32, 128, 0, stream>>>(ws, agent_states, pos, oneh, acts, pols,
                                  w1, b1, b2, se_b, sap_b, av_b, f1_b, f2_w, f2_b,
                                  wout, value);
}

// Round 13
// 51.519 us; speedup vs baseline: 1.1647x; 1.0458x over previous
//
#include <hip/hip_runtime.h>
#include <math.h>

#define NB 4096
#define NA 8
#define BN (NB*NA)   // 32768

// ws layout (u32 words)
#define OFF_SE   0            // se pack:  8 tiles * 512
#define OFF_SAP  4096         // sap pack: 8 tiles * 512
#define OFF_AV   8192         // av pack:  8 tiles * 1024
#define OFF_F1   16384        // f1 pack:  4 tiles * 1024
#define OFF_M    20480        // M pack:   8 tiles * 1024
#define OFF_U    28672        // u: 128 floats
#define OFF_W2P  28800        // conv2 weight A-frag pack: 2 ftiles * 1280 (K=160 pad)
// ws end: 31360 words

typedef short short8 __attribute__((ext_vector_type(8)));
typedef float f32x4 __attribute__((ext_vector_type(4)));

#define MFMA(a,b,c) __builtin_amdgcn_mfma_f32_16x16x32_bf16(a,b,c,0,0,0)

__device__ __forceinline__ float fast_tanh(float x){
    float e = __expf(2.0f*x);
    return 1.0f - 2.0f*__builtin_amdgcn_rcpf(e+1.0f);
}
__device__ __forceinline__ unsigned bfr(float x){
    unsigned u = __float_as_uint(x);
    return (u + 0x7fffu + ((u>>16)&1u)) >> 16;
}
__device__ __forceinline__ unsigned pk2(float lo, float hi){
    return bfr(lo) | (bfr(hi)<<16);
}
__device__ __forceinline__ float bf2f(unsigned short s){
    return __uint_as_float(((unsigned)s)<<16);
}
__device__ __forceinline__ short8 fragld(const unsigned* p){
    union { uint4 u; short8 s; } cv;
    cv.u = *(const uint4*)p;
    return cv.s;
}

// ---------------- kW: pack all weights as A-fragments (pack16 of W^T), compute M, u, w2 pack
__global__ __launch_bounds__(256) void kW(const float* __restrict__ se_w,
        const float* __restrict__ sap_w, const float* __restrict__ av_w,
        const float* __restrict__ f1_w, const float* __restrict__ qw,
        const float* __restrict__ kw, const float* __restrict__ qb,
        const float* __restrict__ w2,
        unsigned* __restrict__ ws){
    int idx = blockIdx.x*256 + threadIdx.x;
    if (idx < 4096){                       // sePk (F=64 pad, rows f2=128)
        int w = idx, tile = w>>9, rem = w&511;
        int ft = rem>>6, r2 = (rem>>2)&15, wi = rem&3;
        int f2 = tile*16 + r2, f1 = ft*8 + wi*2;
        float lo = (f1   < 42)? se_w[f1*128+f2]     : 0.f;
        float hi = (f1+1 < 42)? se_w[(f1+1)*128+f2] : 0.f;
        ws[OFF_SE + w] = pk2(lo,hi);
    } else if (idx < 8192){                // sapPk (F=64 pad, limit 47)
        int w = idx-4096, tile = w>>9, rem = w&511;
        int ft = rem>>6, r2 = (rem>>2)&15, wi = rem&3;
        int f2 = tile*16 + r2, f1 = ft*8 + wi*2;
        float lo = (f1   < 47)? sap_w[f1*128+f2]     : 0.f;
        float hi = (f1+1 < 47)? sap_w[(f1+1)*128+f2] : 0.f;
        ws[OFF_SAP + w] = pk2(lo,hi);
    } else if (idx < 16384){               // avPk (F=128)
        int w = idx-8192, tile = w>>10, rem = w&1023;
        int ft = rem>>6, r2 = (rem>>2)&15, wi = rem&3;
        int f2 = tile*16 + r2, f1 = ft*8 + wi*2;
        ws[OFF_AV + w] = pk2(av_w[f1*128+f2], av_w[(f1+1)*128+f2]);
    } else if (idx < 20480){               // f1Pk (F=128, rows f2=64)
        int w = idx-16384, tile = w>>10, rem = w&1023;
        int ft = rem>>6, r2 = (rem>>2)&15, wi = rem&3;
        int f2 = tile*16 + r2, f1 = ft*8 + wi*2;
        ws[OFF_F1 + w] = pk2(f1_w[f1*64+f2], f1_w[(f1+1)*64+f2]);
    } else if (idx < 28672){               // MPk: M[e][f2] = qw[e]·kw[f2]
        int w = idx-20480, tile = w>>10, rem = w&1023;
        int ft = rem>>6, r2 = (rem>>2)&15, wi = rem&3;
        int f2 = tile*16 + r2, e0 = ft*8 + wi*2;
        float lo=0.f, hi=0.f;
        for (int d=0; d<128; ++d){
            float kv = kw[f2*128+d];
            lo += qw[e0*128+d]*kv;
            hi += qw[(e0+1)*128+d]*kv;
        }
        ws[OFF_M + w] = pk2(lo,hi);
    } else if (idx < 28800){               // u[f] = qb·kw[f]
        int f = idx-28672;
        float a = 0.f;
        for (int d=0; d<128; ++d) a += qb[d]*kw[f*128+d];
        ((float*)ws)[OFF_U + f] = a;
    } else if (idx < 31360){               // conv2 weight A-frags: F=32, K=160 (pad from 144)
        int w = idx-28800;
        int ftile = w/1280, rem = w - ftile*1280;
        int ft = rem>>6, r2 = (rem>>2)&15, wi = rem&3;
        int f = ftile*16 + r2, k0 = ft*8 + wi*2;
        float lo = (k0   < 144)? w2[f*144+k0]   : 0.f;
        float hi = (k0+1 < 144)? w2[f*144+k0+1] : 0.f;
        ws[OFF_W2P + w] = pk2(lo,hi);
    }
}

// ---------------- kF: conv (4 coop passes, conv2 via MFMA) + fused attention/SAP/AV/f1/mix --
// grid 512, 256 threads = 4 waves = 4 tiles = 64 agents = 8 batches per block.
__global__ __launch_bounds__(256,2) void kF(const unsigned* __restrict__ ws,
        const float* __restrict__ xin, const float* __restrict__ pos,
        const float* __restrict__ oneh, const float* __restrict__ acts,
        const float* __restrict__ pols,
        const float* __restrict__ w1, const float* __restrict__ b1,
        const float* __restrict__ b2,
        const float* __restrict__ se_b,
        const float* __restrict__ sap_b, const float* __restrict__ av_b,
        const float* __restrict__ f1_b, const float* __restrict__ f2_w,
        const float* __restrict__ f2_b,
        float* __restrict__ wout, float* __restrict__ value){
    __shared__ unsigned SM[9216];     // conv: in|hpk[4]|ap|pose|w1|b1|b2 ; AB: stage[2][2048]+U1[5120]
    __shared__ unsigned stPk[4096];   // persistent state packs: A[4*512] | P[4*512]
    __shared__ unsigned sA64[2304];   // bf16 [64 rows][72] (stride 36 words, 16B-aligned rows)
    __shared__ unsigned sP64[2304];
    __shared__ float s_w[512];
    __shared__ float s_bias[384];     // sap_b | av_b | f1_b | f2_w
    __shared__ float s_ub[256];       // u | se_b
    const int t = threadIdx.x;
    const int wv = t>>6, lane = t&63;
    const int g = lane>>4, c = lane&15;

    // ===== Phase C: conv encoder =====
    float* c_in   = (float*)SM;             // words 0..1215 (16 ag * 76)
    unsigned* hpk = SM + 1216;              // 4 packs * 1280 words (bf16 B-packs [16 ag][K=160])
    float* c_ap   = (float*)(SM+6336);      // 160
    float* c_pose = (float*)(SM+6496);      // 160
    float* c_w1   = (float*)(SM+6656);      // 432
    float* c_b1   = (float*)(SM+7088);      // 16
    float* c_b2   = (float*)(SM+7104);      // 32 (ends 7136 <= 9216)
    for (int q=t; q<432; q+=256) c_w1[q] = w1[q];
    if (t<16) c_b1[t] = b1[t];
    if (t<32) c_b2[t] = b2[t];
    for (int q=t; q<512; q+=256) hpk[(q>>7)*1280 + 1152 + (q&127)] = 0;   // zero K-pad 144..159
    for (int q=t; q<384; q+=256)
        s_bias[q] = (q<128)? sap_b[q] : (q<256)? av_b[q-128] : (q<320)? f1_b[q-256] : f2_w[q-320];
    s_ub[t] = (t<128)? ((const float*)ws)[OFF_U+t] : se_b[t-128];

    for (int p=0; p<4; ++p){
        const size_t a0g = (size_t)blockIdx.x*64 + p*16;
        for (int q=t; q<1200; q+=256){
            int ag=q/75, r=q-ag*75;
            c_in[ag*76+r] = xin[a0g*75+q];
        }
        for (int q=t; q<160; q+=256){
            int ag=q/10, k=q-ag*10;
            c_ap[q]   = (k<5)? acts[(a0g+ag)*5+k] : pols[(a0g+ag)*5+(k-5)];
            c_pose[q] = (k<2)? pos[(a0g+ag)*2+k]  : oneh[(a0g+ag)*8+(k-2)];
        }
        __syncthreads();
        // conv1: thread = (ag = t&15, oc = t>>4); writes bf16 straight into pack p
        {
            const int ag = t&15, oc = t>>4;
            float w[27];
            #pragma unroll
            for (int i=0;i<27;++i) w[i]=c_w1[oc*27+i];
            float out[9];
            float bb = c_b1[oc];
            #pragma unroll
            for (int q=0;q<9;++q) out[q]=bb;
            #pragma unroll
            for (int ic=0;ic<3;++ic){
                float pin[25];
                #pragma unroll
                for (int i=0;i<25;++i) pin[i]=c_in[ag*76+ic*25+i];
                #pragma unroll
                for (int y=0;y<3;++y)
                  #pragma unroll
                  for (int x=0;x<3;++x)
                    #pragma unroll
                    for (int ky=0;ky<3;++ky)
                      #pragma unroll
                      for (int kx=0;kx<3;++kx)
                        out[y*3+x] += pin[(y+ky)*5+(x+kx)] * w[ic*9+ky*3+kx];
            }
            unsigned short* hp16 = (unsigned short*)(hpk + p*1280);
            #pragma unroll
            for (int q=0;q<9;++q){
                float v = out[q];
                v = (v>=0.f)? v : 0.01f*v;
                int k = oc*9+q;
                int word = (k>>3)*64 + ag*4 + ((k>>1)&3);
                hp16[word*2 + (k&1)] = (unsigned short)bfr(v);
            }
        }
        // pose/act/pol pack words (ft 4..7) -> stPk
        {
            const int ft4 = t>>6, r = (t>>2)&15, wi = t&3;
            const int f0 = 32 + ft4*8 + wi*2;
            float a0=0.f,a1=0.f,p0=0.f,p1=0.f;
            if (f0 < 42){ a0 = c_pose[r*10 + f0-32]; p0 = a0; }
            else if (f0 < 47){ a0 = c_ap[r*10 + f0-42]; p0 = c_ap[r*10+5 + f0-42]; }
            if (f0+1 < 42){ a1 = c_pose[r*10 + f0-31]; p1 = a1; }
            else if (f0+1 < 47){ a1 = c_ap[r*10 + f0-41]; p1 = c_ap[r*10+5 + f0-41]; }
            int word = p*512 + (4+ft4)*64 + r*4 + wi;
            stPk[word]      = pk2(a0,a1);
            stPk[2048+word] = pk2(p0,p1);
        }
        __syncthreads();
    }
    // conv2 as per-wave MFMA: wave wv consumes pack wv ([16 ag] x [32 oc] x K=160)
    {
        const unsigned* hw = hpk + wv*1280;
        f32x4 c2[2];
        c2[0] = (f32x4){0.f,0.f,0.f,0.f};
        c2[1] = (f32x4){0.f,0.f,0.f,0.f};
        #pragma unroll
        for (int kt=0; kt<5; ++kt){
            short8 hb  = fragld(hw + kt*256 + lane*4);
            short8 w0f = fragld(ws + OFF_W2P + kt*256 + lane*4);
            short8 w1f = fragld(ws + OFF_W2P + 1280 + kt*256 + lane*4);
            c2[0] = MFMA(w0f, hb, c2[0]);
            c2[1] = MFMA(w1f, hb, c2[1]);
        }
        #pragma unroll
        for (int ft=0; ft<2; ++ft){
            const float* bp = &c_b2[ft*16 + g*4];
            float d0 = c2[ft][0]+bp[0]; d0 = (d0>=0.f)? d0 : 0.01f*d0;
            float d1 = c2[ft][1]+bp[1]; d1 = (d1>=0.f)? d1 : 0.01f*d1;
            float d2 = c2[ft][2]+bp[2]; d2 = (d2>=0.f)? d2 : 0.01f*d2;
            float d3 = c2[ft][3]+bp[3]; d3 = (d3>=0.f)? d3 : 0.01f*d3;
            int word = wv*512 + (2*ft + (g>>1))*64 + c*4 + (g&1)*2;
            uint2 pw = make_uint2(pk2(d0,d1), pk2(d2,d3));
            *(uint2*)&stPk[word] = pw;
            *(uint2*)&stPk[2048+word] = pw;
        }
    }
    __syncthreads();   // conv regions die; SM becomes AB stage/scratch

    // ===== Phase AB =====
    const int tile = blockIdx.x*4 + wv;
    short8 bfA0 = fragld(&stPk[wv*512 + lane*4]);
    short8 bfA1 = fragld(&stPk[wv*512 + 256 + lane*4]);
    short8 bfP0 = fragld(&stPk[2048 + wv*512 + lane*4]);
    short8 bfP1 = fragld(&stPk[2048 + wv*512 + 256 + lane*4]);
    unsigned (*s_stage)[2048] = (unsigned (*)[2048])&SM[0];
    unsigned* U1 = &SM[4096];
    unsigned* wS = &U1[wv*1280];          // 1024-word per-wave repack scratch
    unsigned* tS = &U1[wv*1280 + 1024];   // 256-word T scratch

    uint4 r0, r1;
#define PREF(off) { r0 = *(const uint4*)(ws + (off) + t*4); \
                    r1 = *(const uint4*)(ws + (off) + 1024 + t*4); }
#define WR(b) { *(uint4*)&s_stage[b][t*4] = r0; *(uint4*)&s_stage[b][1024 + t*4] = r1; }

    PREF(OFF_SE); WR(0);
    __syncthreads();

    // ---- SE chunks c0,c1 -> acc[8] ----
    f32x4 acc[8];
    #pragma unroll
    for (int i=0;i<8;++i) acc[i] = (f32x4){0.f,0.f,0.f,0.f};
    PREF(OFF_SE + 2048);
    #pragma unroll
    for (int ft=0; ft<4; ++ft){
        short8 a0 = fragld(&s_stage[0][ft*512 + lane*4]);
        short8 a1 = fragld(&s_stage[0][ft*512 + 256 + lane*4]);
        acc[ft] = MFMA(a0, bfA0, acc[ft]);
        acc[ft] = MFMA(a1, bfA1, acc[ft]);
    }
    WR(1); __syncthreads();
    PREF(OFF_M);
    #pragma unroll
    for (int ft=4; ft<8; ++ft){
        short8 a0 = fragld(&s_stage[1][(ft-4)*512 + lane*4]);
        short8 a1 = fragld(&s_stage[1][(ft-4)*512 + 256 + lane*4]);
        acc[ft] = MFMA(a0, bfA0, acc[ft]);
        acc[ft] = MFMA(a1, bfA1, acc[ft]);
    }
    WR(0);
    // E build -> wS, cache ef[4]
    #pragma unroll
    for (int ft=0; ft<8; ++ft){
        const float* bp = &s_ub[128 + ft*16 + g*4];
        float d0 = fast_tanh(acc[ft][0]+bp[0]);
        float d1 = fast_tanh(acc[ft][1]+bp[1]);
        float d2 = fast_tanh(acc[ft][2]+bp[2]);
        float d3 = fast_tanh(acc[ft][3]+bp[3]);
        int word = (2*ft + (g>>1))*64 + c*4 + (g&1)*2;
        *(uint2*)&wS[word] = make_uint2(pk2(d0,d1), pk2(d2,d3));
    }
    short8 ef[4];
    #pragma unroll
    for (int kt=0; kt<4; ++kt) ef[kt] = fragld(&wS[kt*256 + lane*4]);
    __syncthreads();

    // ---- M chunks c2..c5, fused T-write + logits ----
    f32x4 L = (f32x4){0.f,0.f,0.f,0.f};
    #pragma unroll
    for (int i=0; i<4; ++i){
        const int nextOff = (i<3)? (OFF_M + (i+1)*2048) : OFF_SAP;
        PREF(nextOff);
        f32x4 a2[2];
        a2[0] = (f32x4){0.f,0.f,0.f,0.f};
        a2[1] = (f32x4){0.f,0.f,0.f,0.f};
        #pragma unroll
        for (int ftl=0; ftl<2; ++ftl)
          #pragma unroll
          for (int kt=0; kt<4; ++kt){
            short8 mf = fragld(&s_stage[i&1][ftl*1024 + kt*256 + lane*4]);
            a2[ftl] = MFMA(mf, ef[kt], a2[ftl]);
          }
        WR((i+1)&1);
        #pragma unroll
        for (int ftl=0; ftl<2; ++ftl){
            const float* up = &s_ub[(2*i+ftl)*16 + g*4];
            int word = (2*ftl + (g>>1))*64 + c*4 + (g&1)*2;
            *(uint2*)&tS[word] = make_uint2(pk2(a2[ftl][0]+up[0], a2[ftl][1]+up[1]),
                                            pk2(a2[ftl][2]+up[2], a2[ftl][3]+up[3]));
        }
        short8 tf = fragld(&tS[lane*4]);
        L = MFMA(tf, ef[i], L);
        __syncthreads();
    }
    // softmax -> s_w + wout
    {
        float sc[4];
        #pragma unroll
        for (int q=0;q<4;++q) sc[q] = L[q]*0.08838834764831845f;
        #pragma unroll
        for (int q=0;q<4;++q){
            float m = sc[q];
            m = fmaxf(m, __shfl_xor(m,1));
            m = fmaxf(m, __shfl_xor(m,2));
            m = fmaxf(m, __shfl_xor(m,4));
            float ex = __expf(sc[q]-m);
            float su = ex;
            su += __shfl_xor(su,1);
            su += __shfl_xor(su,2);
            su += __shfl_xor(su,4);
            sc[q] = ex/su;
        }
        if ((c>>3) == (g>>1)){
            int lb = wv*2 + (g>>1);
            int batch = tile*2 + (g>>1);
            int idx = ((g&1)*4)*8 + (c&7);
            #pragma unroll
            for (int q=0;q<4;++q){
                float v = sc[q];
                wout[batch*64 + idx + q*8] = v;
                s_w[lb*64 + idx + q*8] = v;
            }
        }
    }

    // ---- SAP chunks c6,c7 -> aS[2][8] ----
    f32x4 aS[2][8];
    #pragma unroll
    for (int v=0;v<2;++v)
      #pragma unroll
      for (int i=0;i<8;++i) aS[v][i] = (f32x4){0.f,0.f,0.f,0.f};
    PREF(OFF_SAP + 2048);
    #pragma unroll
    for (int ft=0; ft<4; ++ft){
        short8 a0 = fragld(&s_stage[0][ft*512 + lane*4]);
        short8 a1 = fragld(&s_stage[0][ft*512 + 256 + lane*4]);
        aS[0][ft] = MFMA(a0, bfA0, aS[0][ft]);
        aS[0][ft] = MFMA(a1, bfA1, aS[0][ft]);
        aS[1][ft] = MFMA(a0, bfP0, aS[1][ft]);
        aS[1][ft] = MFMA(a1, bfP1, aS[1][ft]);
    }
    WR(1); __syncthreads();
    PREF(OFF_AV);
    #pragma unroll
    for (int ft=4; ft<8; ++ft){
        short8 a0 = fragld(&s_stage[1][(ft-4)*512 + lane*4]);
        short8 a1 = fragld(&s_stage[1][(ft-4)*512 + 256 + lane*4]);
        aS[0][ft] = MFMA(a0, bfA0, aS[0][ft]);
        aS[0][ft] = MFMA(a1, bfA1, aS[0][ft]);
        aS[1][ft] = MFMA(a0, bfP0, aS[1][ft]);
        aS[1][ft] = MFMA(a1, bfP1, aS[1][ft]);
    }
    WR(0);
    // SAP build (variant A then P through the single scratch), cache frags
    short8 spA[4], spP[4];
    #pragma unroll
    for (int ft=0; ft<8; ++ft){
        const float* bp = &s_bias[ft*16 + g*4];
        float d0 = fast_tanh(aS[0][ft][0]+bp[0]);
        float d1 = fast_tanh(aS[0][ft][1]+bp[1]);
        float d2 = fast_tanh(aS[0][ft][2]+bp[2]);
        float d3 = fast_tanh(aS[0][ft][3]+bp[3]);
        int word = (2*ft + (g>>1))*64 + c*4 + (g&1)*2;
        *(uint2*)&wS[word] = make_uint2(pk2(d0,d1), pk2(d2,d3));
    }
    #pragma unroll
    for (int kt=0; kt<4; ++kt) spA[kt] = fragld(&wS[kt*256 + lane*4]);
    #pragma unroll
    for (int ft=0; ft<8; ++ft){
        const float* bp = &s_bias[ft*16 + g*4];
        float d0 = fast_tanh(aS[1][ft][0]+bp[0]);
        float d1 = fast_tanh(aS[1][ft][1]+bp[1]);
        float d2 = fast_tanh(aS[1][ft][2]+bp[2]);
        float d3 = fast_tanh(aS[1][ft][3]+bp[3]);
        int word = (2*ft + (g>>1))*64 + c*4 + (g&1)*2;
        *(uint2*)&wS[word] = make_uint2(pk2(d0,d1), pk2(d2,d3));
    }
    #pragma unroll
    for (int kt=0; kt<4; ++kt) spP[kt] = fragld(&wS[kt*256 + lane*4]);
    __syncthreads();

    // ---- AV chunks c8..c11 -> aV[2][8] ----
    f32x4 aV[2][8];
    #pragma unroll
    for (int v=0;v<2;++v)
      #pragma unroll
      for (int i=0;i<8;++i) aV[v][i] = (f32x4){0.f,0.f,0.f,0.f};
    short8 avA[4], avP[4];
    #pragma unroll
    for (int i=0; i<4; ++i){
        const int nextOff = (i<3)? (OFF_AV + (i+1)*2048) : OFF_F1;
        PREF(nextOff);
        #pragma unroll
        for (int ftl=0; ftl<2; ++ftl){
            const int ft = 2*i + ftl;
            #pragma unroll
            for (int kt=0; kt<4; ++kt){
                short8 af = fragld(&s_stage[i&1][ftl*1024 + kt*256 + lane*4]);
                aV[0][ft] = MFMA(af, spA[kt], aV[0][ft]);
                aV[1][ft] = MFMA(af, spP[kt], aV[1][ft]);
            }
        }
        WR((i+1)&1);
        if (i==3){
            // AV build (A then P through scratch), cache frags
            #pragma unroll
            for (int ft=0; ft<8; ++ft){
                const float* bp = &s_bias[128 + ft*16 + g*4];
                float d0 = fast_tanh(aV[0][ft][0]+bp[0]);
                float d1 = fast_tanh(aV[0][ft][1]+bp[1]);
                float d2 = fast_tanh(aV[0][ft][2]+bp[2]);
                float d3 = fast_tanh(aV[0][ft][3]+bp[3]);
                int word = (2*ft + (g>>1))*64 + c*4 + (g&1)*2;
                *(uint2*)&wS[word] = make_uint2(pk2(d0,d1), pk2(d2,d3));
            }
            #pragma unroll
            for (int kt=0; kt<4; ++kt) avA[kt] = fragld(&wS[kt*256 + lane*4]);
            #pragma unroll
            for (int ft=0; ft<8; ++ft){
                const float* bp = &s_bias[128 + ft*16 + g*4];
                float d0 = fast_tanh(aV[1][ft][0]+bp[0]);
                float d1 = fast_tanh(aV[1][ft][1]+bp[1]);
                float d2 = fast_tanh(aV[1][ft][2]+bp[2]);
                float d3 = fast_tanh(aV[1][ft][3]+bp[3]);
                int word = (2*ft + (g>>1))*64 + c*4 + (g&1)*2;
                *(uint2*)&wS[word] = make_uint2(pk2(d0,d1), pk2(d2,d3));
            }
            #pragma unroll
            for (int kt=0; kt<4; ++kt) avP[kt] = fragld(&wS[kt*256 + lane*4]);
        }
        __syncthreads();
    }

    // ---- F1 chunks c12,c13 -> aF[2][4] ----
    f32x4 aF[2][4];
    #pragma unroll
    for (int v=0;v<2;++v)
      #pragma unroll
      for (int i=0;i<4;++i) aF[v][i] = (f32x4){0.f,0.f,0.f,0.f};
    PREF(OFF_F1 + 2048);
    #pragma unroll
    for (int ftl=0; ftl<2; ++ftl)
      #pragma unroll
      for (int kt=0; kt<4; ++kt){
        short8 af = fragld(&s_stage[0][ftl*1024 + kt*256 + lane*4]);
        aF[0][ftl] = MFMA(af, avA[kt], aF[0][ftl]);
        aF[1][ftl] = MFMA(af, avP[kt], aF[1][ftl]);
      }
    WR(1); __syncthreads();
    #pragma unroll
    for (int ftl=0; ftl<2; ++ftl)
      #pragma unroll
      for (int kt=0; kt<4; ++kt){
        short8 af = fragld(&s_stage[1][ftl*1024 + kt*256 + lane*4]);
        aF[0][2+ftl] = MFMA(af, avA[kt], aF[0][2+ftl]);
        aF[1][2+ftl] = MFMA(af, avP[kt], aF[1][2+ftl]);
      }
    {
        int row = wv*16 + c;
        #pragma unroll
        for (int v=0;v<2;++v){
            unsigned* dst = v? sP64 : sA64;
            #pragma unroll
            for (int ft=0; ft<4; ++ft){
                int idx = row*36 + ft*8 + 2*g;
                *(uint2*)&dst[idx] = make_uint2(pk2(aF[v][ft][0], aF[v][ft][1]),
                                                pk2(aF[v][ft][2], aF[v][ft][3]));
            }
        }
    }
    __syncthreads();
    // ---- tail: b64 (vectorized) + final mix (vectorized) ----
    float* s_b64 = (float*)U1;  // [64 rows][68] floats = 4352 words <= 5120
    {
        // thread = (bqa = t>>2 in [0,64), ccg = t&3): computes b64[bqa][ccg*16 .. +16)
        const int bqa = t>>2, ccg = t&3;
        const int bq = bqa>>3, a = bqa&7;
        const float* wp = &s_w[bq*64 + a*8];
        f32x4 av0 = (f32x4){0.f,0.f,0.f,0.f};
        f32x4 av1 = (f32x4){0.f,0.f,0.f,0.f};
        f32x4 av2 = (f32x4){0.f,0.f,0.f,0.f};
        f32x4 av3 = (f32x4){0.f,0.f,0.f,0.f};
        #pragma unroll
        for (int j=0;j<8;++j){
            float wj = wp[j];
            const unsigned* rp = &sA64[(bq*8+j)*36 + ccg*8];
            short8 v0 = fragld(rp);
            short8 v1 = fragld(rp+4);
            av0[0] += wj*bf2f((unsigned short)v0[0]); av0[1] += wj*bf2f((unsigned short)v0[1]);
            av0[2] += wj*bf2f((unsigned short)v0[2]); av0[3] += wj*bf2f((unsigned short)v0[3]);
            av1[0] += wj*bf2f((unsigned short)v0[4]); av1[1] += wj*bf2f((unsigned short)v0[5]);
            av1[2] += wj*bf2f((unsigned short)v0[6]); av1[3] += wj*bf2f((unsigned short)v0[7]);
            av2[0] += wj*bf2f((unsigned short)v1[0]); av2[1] += wj*bf2f((unsigned short)v1[1]);
            av2[2] += wj*bf2f((unsigned short)v1[2]); av2[3] += wj*bf2f((unsigned short)v1[3]);
            av3[0] += wj*bf2f((unsigned short)v1[4]); av3[1] += wj*bf2f((unsigned short)v1[5]);
            av3[2] += wj*bf2f((unsigned short)v1[6]); av3[3] += wj*bf2f((unsigned short)v1[7]);
        }
        float* outp = &s_b64[bqa*68 + ccg*16];
        *(f32x4*)&outp[0]  = av0;
        *(f32x4*)&outp[4]  = av1;
        *(f32x4*)&outp[8]  = av2;
        *(f32x4*)&outp[12] = av3;
    }
    __syncthreads();
    #pragma unroll
    for (int k=0; k<2; ++k){
        int o = t + 256*k;
        int bq = o>>6, a = (o>>3)&7, i = o&7;
        float w_ai = s_w[bq*64 + a*8 + i];
        const float* pb = &s_b64[(bq*8+a)*68];
        const unsigned* pA = &sA64[(bq*8+i)*36];
        const unsigned* pP = &sP64[(bq*8+i)*36];
        float acc5 = 0.f;
        #pragma unroll
        for (int c8=0; c8<8; ++c8){
            f32x4 pb0 = *(const f32x4*)&pb[c8*8];
            f32x4 pb1 = *(const f32x4*)&pb[c8*8+4];
            short8 va = fragld(pA + c8*4);
            short8 vp = fragld(pP + c8*4);
            const float* fb = &s_bias[256 + c8*8];
            const float* fw = &s_bias[320 + c8*8];
            #pragma unroll
            for (int e=0;e<4;++e){
                float dd = bf2f((unsigned short)vp[e]) - bf2f((unsigned short)va[e]);
                acc5 += fast_tanh(pb0[e] + w_ai*dd + fb[e]) * fw[e];
            }
            #pragma unroll
            for (int e=0;e<4;++e){
                float dd = bf2f((unsigned short)vp[4+e]) - bf2f((unsigned short)va[4+e]);
                acc5 += fast_tanh(pb1[e] + w_ai*dd + fb[4+e]) * fw[4+e];
            }
        }
        value[(size_t)blockIdx.x*512 + o] = acc5 + f2_b[0];
    }
#undef PREF
#undef WR
}

extern "C" void kernel_launch(void* const* d_in, const int* in_sizes, int n_in,
                              void* d_out, int out_size, void* d_ws, size_t ws_size,
                              hipStream_t stream){
    const float* agent_states = (const float*)d_in[0];
    const float* pos    = (const float*)d_in[1];
    const float* oneh   = (const float*)d_in[2];
    const float* pols   = (const float*)d_in[3];
    const float* acts   = (const float*)d_in[4];
    const float* w1     = (const float*)d_in[5];
    const float* b1     = (const float*)d_in[6];
    const float* w2     = (const float*)d_in[7];
    const float* b2     = (const float*)d_in[8];
    const float* se_w   = (const float*)d_in[9];
    const float* se_b   = (const float*)d_in[10];
    const float* key_w  = (const float*)d_in[11];
    const float* query_w= (const float*)d_in[13];
    const float* query_b= (const float*)d_in[14];
    const float* sap_w  = (const float*)d_in[15];
    const float* sap_b  = (const float*)d_in[16];
    const float* av_w   = (const float*)d_in[17];
    const float* av_b   = (const float*)d_in[18];
    const float* f1_w   = (const float*)d_in[19];
    const float* f1_b   = (const float*)d_in[20];
    const float* f2_w   = (const float*)d_in[21];
    const float* f2_b   = (const float*)d_in[22];

    unsigned* ws = (unsigned*)d_ws;

    float* value = (float*)d_out;
    float* wout  = value + (size_t)NB*NA*NA;

    kW<<<123, 256, 0, stream>>>(se_w, sap_w, av_w, f1_w, query_w, key_w, query_b, w2, ws);
    kF<<<BN/64, 256, 0, stream>>>(ws, agent_states, pos, oneh, acts, pols,
                                  w1, b1, b2, se_b, sap_b, av_b, f1_b, f2_w, f2_b,
                                  wout, value);
}